// Round 1
// 187.096 us; speedup vs baseline: 1.0108x; 1.0108x over previous
//
#include <hip/hip_runtime.h>

#define N_NODES 50000
#define N_EDGES 800000
#define CH 64
#define OUT_OFF_STD (N_NODES * CH)        // 3,200,000
#define OUT_OFF_KL  (2 * N_NODES * CH)    // 6,400,000
#define CAP 64                            // slots/node; in-degree ~Poisson(16)

#define NGRP 8                            // XCD groups (blockIdx & 7 heuristic)
#define NPG 6250                          // nodes per group (8*6250 = 50000)
#define FILL_CHUNK 2048
#define FILL_CHUNKS 391                   // 391*2048 = 800768 >= 800000
#define FILL_BLOCKS (NGRP * FILL_CHUNKS)  // 3128
#define GEMM_BLOCKS 782                   // ceil(50000/64)
#define GATHER_CHUNKS 1563                // ceil(6250/4)
#define ZERO_BLOCKS 196                   // ceil(50000/256)

typedef __attribute__((ext_vector_type(8))) short short8;
typedef __attribute__((ext_vector_type(4))) float f32x4;

__device__ __forceinline__ int rl_i(unsigned v, int lane) {
    return __builtin_amdgcn_readlane((int)v, lane);
}
// fp32 -> bf16 round-to-nearest-even (returns low 16 bits)
__device__ __forceinline__ unsigned f2bf(float f) {
    unsigned u = __float_as_uint(f);
    return (u + 0x7fffu + ((u >> 16) & 1u)) >> 16;
}

// ---------------------------------------------------------------------------
// Kernel A: W + KL (block 0) + cur zeroing (blocks 1..196, replaces the
// hipMemsetAsync dispatch -> one fewer serial bubble).
// fragB[((c*2+h)*64 + lane)*8 + j] = bf16(W[h*32+(lane>>4)*8+j][c*16+(lane&15)])
// ---------------------------------------------------------------------------
__global__ __launch_bounds__(256) void wkl_kernel(
    const float* __restrict__ mu_m, const float* __restrict__ ls_m,
    const float* __restrict__ eps_m,
    const float* __restrict__ mu_s, const float* __restrict__ ls_s,
    const float* __restrict__ eps_s,
    unsigned short* __restrict__ fragBm, unsigned short* __restrict__ fragBv,
    float* __restrict__ kl_out, int* __restrict__ cur)
{
    if (blockIdx.x != 0) {                // ---- cur-zero role ----
        int i = ((int)blockIdx.x - 1) * 256 + (int)threadIdx.x;
        if (i < N_NODES) cur[i] = 0;
        return;
    }
    __shared__ unsigned short Wm[CH * CH];
    __shared__ unsigned short Wv[CH * CH];
    float kl = 0.0f;
    for (int i = threadIdx.x; i < CH * CH; i += 256) {
        float mu = mu_m[i], ls = ls_m[i];
        Wm[i] = (unsigned short)f2bf(mu + eps_m[i] * expf(ls));
        kl += 0.5f * (expf(2.0f * ls) + mu * mu - 2.0f * ls - 1.0f);
        mu = mu_s[i]; ls = ls_s[i];
        Wv[i] = (unsigned short)f2bf(mu + eps_s[i] * expf(ls));
        kl += 0.5f * (expf(2.0f * ls) + mu * mu - 2.0f * ls - 1.0f);
    }
    __syncthreads();
    for (int f = threadIdx.x; f < CH * CH; f += 256) {
        int j = f & 7, l = (f >> 3) & 63, ch = f >> 9;   // ch = c*2 + h
        int k = (ch & 1) * 32 + ((l >> 4) & 3) * 8 + j;
        int n = (ch >> 1) * 16 + (l & 15);
        fragBm[f] = Wm[k * CH + n];
        fragBv[f] = Wv[k * CH + n];
    }
    for (int off = 32; off > 0; off >>= 1)
        kl += __shfl_down(kl, off, 64);
    __shared__ float red[4];
    if ((threadIdx.x & 63) == 0) red[threadIdx.x >> 6] = kl;
    __syncthreads();
    if (threadIdx.x == 0)
        kl_out[0] = red[0] + red[1] + red[2] + red[3];
}

// ---------------------------------------------------------------------------
// Kernel B: fused XCD-affine fill + MFMA-GEMM. Zero LDS.
//  Fill role restructured for ILP: 8 edges/thread loaded via dwordx4 (dst AND
//  src/w unconditionally -- line-level fetch is ~the same as divergent 4B
//  gathers), all 8 atomicAdds issued before any store consumes a slot ->
//  8 returning atomics in flight per thread instead of ~1.
// ---------------------------------------------------------------------------
__global__ __launch_bounds__(256) void gemfill_kernel(
    const float* __restrict__ mean, const float* __restrict__ stdv,
    const unsigned short* __restrict__ fragBm,
    const unsigned short* __restrict__ fragBv,
    const int* __restrict__ ei, const float* __restrict__ ew,
    int* __restrict__ cur, uint2* __restrict__ bins,
    unsigned* __restrict__ sup)
{
    const int tid = threadIdx.x;

    if (blockIdx.x < FILL_BLOCKS) {      // ---- fill role, XCD-affine ----
        const int g = blockIdx.x & (NGRP - 1);
        const int chunk = blockIdx.x >> 3;
        const int base = chunk * FILL_CHUNK + tid * 8;
        const int lo = g * NPG;

        int d[8], s[8]; float w[8];
        if (base + 8 <= N_EDGES) {
            int4 d0 = *(const int4*)(ei + N_EDGES + base);
            int4 d1 = *(const int4*)(ei + N_EDGES + base + 4);
            d[0] = d0.x; d[1] = d0.y; d[2] = d0.z; d[3] = d0.w;
            d[4] = d1.x; d[5] = d1.y; d[6] = d1.z; d[7] = d1.w;
            int4 s0 = *(const int4*)(ei + base);
            int4 s1 = *(const int4*)(ei + base + 4);
            s[0] = s0.x; s[1] = s0.y; s[2] = s0.z; s[3] = s0.w;
            s[4] = s1.x; s[5] = s1.y; s[6] = s1.z; s[7] = s1.w;
            float4 w0 = *(const float4*)(ew + base);
            float4 w1 = *(const float4*)(ew + base + 4);
            w[0] = w0.x; w[1] = w0.y; w[2] = w0.z; w[3] = w0.w;
            w[4] = w1.x; w[5] = w1.y; w[6] = w1.z; w[7] = w1.w;
        } else {
#pragma unroll
            for (int t = 0; t < 8; ++t) {
                bool v = (base + t) < N_EDGES;
                d[t] = v ? ei[N_EDGES + base + t] : -1;
                s[t] = v ? ei[base + t] : 0;
                w[t] = v ? ew[base + t] : 0.0f;
            }
        }

        int slot[8];
#pragma unroll
        for (int t = 0; t < 8; ++t) {
            bool act = (unsigned)(d[t] - lo) < (unsigned)NPG;
            slot[t] = act ? atomicAdd(&cur[d[t]], 1) : CAP;
        }
#pragma unroll
        for (int t = 0; t < 8; ++t) {
            if (slot[t] < CAP)
                bins[(size_t)d[t] * CAP + slot[t]] =
                    make_uint2((unsigned)s[t], __float_as_uint(w[t]));
        }
        return;
    }

    // ---- gemm role ----
    const int lane = tid & 63, wave = tid >> 6;
    const int row0 = (blockIdx.x - FILL_BLOCKS) * 64 + wave * 16;
    if (row0 >= N_NODES) return;

    const int m = lane & 15;             // A row within tile
    const int q = (lane >> 4) & 3;       // k quad
    const float* mrow = mean + (size_t)(row0 + m) * CH + q * 8;
    const float* srow = stdv + (size_t)(row0 + m) * CH + q * 8;

    short8 aM[2], aV[2];
#pragma unroll
    for (int h = 0; h < 2; ++h) {        // k = h*32 + q*8 + j
        float4 x0 = *(const float4*)(mrow + h * 32);
        float4 x1 = *(const float4*)(mrow + h * 32 + 4);
        float4 s0 = *(const float4*)(srow + h * 32);
        float4 s1 = *(const float4*)(srow + h * 32 + 4);
        aM[h][0] = (short)f2bf(x0.x); aM[h][1] = (short)f2bf(x0.y);
        aM[h][2] = (short)f2bf(x0.z); aM[h][3] = (short)f2bf(x0.w);
        aM[h][4] = (short)f2bf(x1.x); aM[h][5] = (short)f2bf(x1.y);
        aM[h][6] = (short)f2bf(x1.z); aM[h][7] = (short)f2bf(x1.w);
        aV[h][0] = (short)f2bf(s0.x * s0.x); aV[h][1] = (short)f2bf(s0.y * s0.y);
        aV[h][2] = (short)f2bf(s0.z * s0.z); aV[h][3] = (short)f2bf(s0.w * s0.w);
        aV[h][4] = (short)f2bf(s1.x * s1.x); aV[h][5] = (short)f2bf(s1.y * s1.y);
        aV[h][6] = (short)f2bf(s1.z * s1.z); aV[h][7] = (short)f2bf(s1.w * s1.w);
    }

    f32x4 accM[4], accV[4];
#pragma unroll
    for (int c = 0; c < 4; ++c) {
        accM[c] = (f32x4)0.0f;
        accV[c] = (f32x4)0.0f;
    }
#pragma unroll
    for (int c = 0; c < 4; ++c) {
#pragma unroll
        for (int h = 0; h < 2; ++h) {
            short8 bm = *(const short8*)(fragBm + ((c * 2 + h) * 64 + lane) * 8);
            short8 bv = *(const short8*)(fragBv + ((c * 2 + h) * 64 + lane) * 8);
            accM[c] = __builtin_amdgcn_mfma_f32_16x16x32_bf16(aM[h], bm, accM[c], 0, 0, 0);
            accV[c] = __builtin_amdgcn_mfma_f32_16x16x32_bf16(aV[h], bv, accV[c], 0, 0, 0);
        }
    }

    // C/D layout: col = lane&15, row = (lane>>4)*4 + reg  [m89-verified]
    const int rg = lane >> 4;
#pragma unroll
    for (int c = 0; c < 4; ++c) {
#pragma unroll
        for (int r = 0; r < 4; ++r) {
            int node = row0 + rg * 4 + r;
            sup[(size_t)node * CH + c * 16 + m] =
                f2bf(accM[c][r]) | (f2bf(accV[c][r]) << 16);
        }
    }
}

// ---------------------------------------------------------------------------
// Kernel C: pull-gather, XCD-affine (same g = blockIdx&7 mapping as fill, so
// a group's bins/cur are L2-resident on its XCD). One wave per node, lane =
// channel, 8 independent sup loads in flight per iter. No atomics, no LDS.
// ---------------------------------------------------------------------------
__global__ __launch_bounds__(256) void gather_kernel(
    const int* __restrict__ cur, const uint2* __restrict__ bins,
    const unsigned* __restrict__ sup, float* __restrict__ out)
{
    const int g = blockIdx.x & (NGRP - 1);
    const int cid = blockIdx.x >> 3;
    const int wave = threadIdx.x >> 6;
    const int col = threadIdx.x & 63;
    const int loc = cid * 4 + wave;
    if (loc >= NPG) return;
    const int n = g * NPG + loc;

    int cnt = cur[n];
    if (cnt > CAP) cnt = CAP;
    uint2 p = make_uint2(0u, 0u);
    if (col < cnt) p = bins[(size_t)n * CAP + col];

    float accM = 0.0f, accV = 0.0f;
    for (int i = 0; i < cnt; i += 8) {
        int   s[8];
        float w[8];
#pragma unroll
        for (int t = 0; t < 8; ++t) {
            bool v = (i + t < cnt);
            s[t] = v ? rl_i(p.x, i + t) : 0;
            w[t] = v ? __uint_as_float((unsigned)rl_i(p.y, i + t)) : 0.0f;
        }
        unsigned q[8];
#pragma unroll
        for (int t = 0; t < 8; ++t)
            q[t] = sup[(size_t)s[t] * CH + col];
#pragma unroll
        for (int t = 0; t < 8; ++t) {
            float mm = __uint_as_float(q[t] << 16);
            float vv = __uint_as_float(q[t] & 0xFFFF0000u);
            accM += w[t] * mm;
            accV += (w[t] * w[t]) * vv;
        }
    }
    out[(size_t)n * CH + col] = accM;
    out[OUT_OFF_STD + (size_t)n * CH + col] = sqrtf(expf(accV) + 1e-6f);
}

extern "C" void kernel_launch(void* const* d_in, const int* in_sizes, int n_in,
                              void* d_out, int out_size, void* d_ws, size_t ws_size,
                              hipStream_t stream)
{
    const float* mean  = (const float*)d_in[0];
    const float* stdv  = (const float*)d_in[1];
    const int*   ei    = (const int*)d_in[2];
    const float* ew    = (const float*)d_in[3];
    const float* mu_m  = (const float*)d_in[4];
    const float* ls_m  = (const float*)d_in[5];
    const float* eps_m = (const float*)d_in[6];
    const float* ls_s  = (const float*)d_in[8];
    const float* mu_s  = (const float*)d_in[7];
    const float* eps_s = (const float*)d_in[9];

    float* out = (float*)d_out;
    // layout (16B-aligned): cur | sup | bins | fragBm | fragBv
    int*            cur    = (int*)d_ws;                           // 50000 i
    unsigned*       sup    = (unsigned*)(cur + N_NODES);           // 3.2M u32
    uint2*          bins   = (uint2*)(sup + (size_t)N_NODES * CH); // 3.2M uint2
    unsigned short* fragBm = (unsigned short*)(bins + (size_t)N_NODES * CAP);
    unsigned short* fragBv = fragBm + CH * CH;

    wkl_kernel<<<1 + ZERO_BLOCKS, 256, 0, stream>>>(
        mu_m, ls_m, eps_m, mu_s, ls_s, eps_s,
        fragBm, fragBv, out + OUT_OFF_KL, cur);
    gemfill_kernel<<<FILL_BLOCKS + GEMM_BLOCKS, 256, 0, stream>>>(
        mean, stdv, fragBm, fragBv, ei, ew, cur, bins, sup);
    gather_kernel<<<NGRP * GATHER_CHUNKS, 256, 0, stream>>>(cur, bins, sup, out);
}

// Round 2
// 176.309 us; speedup vs baseline: 1.0726x; 1.0612x over previous
//
#include <hip/hip_runtime.h>

#define N_NODES 50000
#define N_EDGES 800000
#define CH 64
#define OUT_OFF_STD (N_NODES * CH)        // 3,200,000
#define OUT_OFF_KL  (2 * N_NODES * CH)    // 6,400,000
#define CAP 64                            // slots/node (512B region, 64B-line aligned)
#define CAP_USE 62                        // slot 63 = embedded counter; 62 fits Poisson(16) tail

#define NGRP 8                            // XCD groups (blockIdx & 7 heuristic)
#define NPG 6250                          // nodes per group (8*6250 = 50000)
#define FILL_CHUNK 2048
#define FILL_CHUNKS 391                   // 391*2048 = 800768 >= 800000
#define FILL_BLOCKS (NGRP * FILL_CHUNKS)  // 3128
#define GEMM_BLOCKS 782                   // ceil(50000/64)
#define GATHER_CHUNKS 1563                // ceil(6250/4)
#define ZERO_GRID 208                     // blocks 8..207 zero counters XCD-affinely

typedef __attribute__((ext_vector_type(8))) short short8;
typedef __attribute__((ext_vector_type(4))) float f32x4;

__device__ __forceinline__ int rl_i(unsigned v, int lane) {
    return __builtin_amdgcn_readlane((int)v, lane);
}
// fp32 -> bf16 round-to-nearest-even (returns low 16 bits)
__device__ __forceinline__ unsigned f2bf(float f) {
    unsigned u = __float_as_uint(f);
    return (u + 0x7fffu + ((u >> 16) & 1u)) >> 16;
}
// per-node counter lives in slot 63 of the node's bins region -> one counter
// per 64B line, private to that node. Kills same-line atomic serialization.
__device__ __forceinline__ int* cnt_ptr(uint2* bins, int node) {
    return (int*)(bins + (size_t)node * CAP + 63);
}

// ---------------------------------------------------------------------------
// Kernel A: W + KL (block 0) + XCD-affine counter zeroing (blocks 8..207,
// g = blockIdx&7 matches fill's mapping so counter lines are warm in the
// owning XCD's L2 before the atomics hit them).
// fragB[((c*2+h)*64 + lane)*8 + j] = bf16(W[h*32+(lane>>4)*8+j][c*16+(lane&15)])
// ---------------------------------------------------------------------------
__global__ __launch_bounds__(256) void wkl_kernel(
    const float* __restrict__ mu_m, const float* __restrict__ ls_m,
    const float* __restrict__ eps_m,
    const float* __restrict__ mu_s, const float* __restrict__ ls_s,
    const float* __restrict__ eps_s,
    unsigned short* __restrict__ fragBm, unsigned short* __restrict__ fragBv,
    float* __restrict__ kl_out, uint2* __restrict__ bins)
{
    if (blockIdx.x != 0) {                // ---- counter-zero role ----
        if (blockIdx.x < 8) return;
        const int g = blockIdx.x & (NGRP - 1);
        const int loc = ((int)(blockIdx.x >> 3) - 1) * 256 + (int)threadIdx.x;
        if (loc < NPG) *cnt_ptr(bins, g * NPG + loc) = 0;
        return;
    }
    __shared__ unsigned short Wm[CH * CH];
    __shared__ unsigned short Wv[CH * CH];
    float kl = 0.0f;
    for (int i = threadIdx.x; i < CH * CH; i += 256) {
        float mu = mu_m[i], ls = ls_m[i];
        Wm[i] = (unsigned short)f2bf(mu + eps_m[i] * expf(ls));
        kl += 0.5f * (expf(2.0f * ls) + mu * mu - 2.0f * ls - 1.0f);
        mu = mu_s[i]; ls = ls_s[i];
        Wv[i] = (unsigned short)f2bf(mu + eps_s[i] * expf(ls));
        kl += 0.5f * (expf(2.0f * ls) + mu * mu - 2.0f * ls - 1.0f);
    }
    __syncthreads();
    for (int f = threadIdx.x; f < CH * CH; f += 256) {
        int j = f & 7, l = (f >> 3) & 63, ch = f >> 9;   // ch = c*2 + h
        int k = (ch & 1) * 32 + ((l >> 4) & 3) * 8 + j;
        int n = (ch >> 1) * 16 + (l & 15);
        fragBm[f] = Wm[k * CH + n];
        fragBv[f] = Wv[k * CH + n];
    }
    for (int off = 32; off > 0; off >>= 1)
        kl += __shfl_down(kl, off, 64);
    __shared__ float red[4];
    if ((threadIdx.x & 63) == 0) red[threadIdx.x >> 6] = kl;
    __syncthreads();
    if (threadIdx.x == 0)
        kl_out[0] = red[0] + red[1] + red[2] + red[3];
}

// ---------------------------------------------------------------------------
// Kernel B: fused XCD-affine fill + MFMA-GEMM. Zero LDS.
//  Fill: 8 edges/thread via dwordx4; all 8 atomics issued back-to-back.
//  Counter atomics now hit one line per node (embedded in bins slot 63).
// ---------------------------------------------------------------------------
__global__ __launch_bounds__(256) void gemfill_kernel(
    const float* __restrict__ mean, const float* __restrict__ stdv,
    const unsigned short* __restrict__ fragBm,
    const unsigned short* __restrict__ fragBv,
    const int* __restrict__ ei, const float* __restrict__ ew,
    uint2* __restrict__ bins, unsigned* __restrict__ sup)
{
    const int tid = threadIdx.x;

    if (blockIdx.x < FILL_BLOCKS) {      // ---- fill role, XCD-affine ----
        const int g = blockIdx.x & (NGRP - 1);
        const int chunk = blockIdx.x >> 3;
        const int base = chunk * FILL_CHUNK + tid * 8;
        const int lo = g * NPG;

        int d[8], s[8]; float w[8];
        if (base + 8 <= N_EDGES) {
            int4 d0 = *(const int4*)(ei + N_EDGES + base);
            int4 d1 = *(const int4*)(ei + N_EDGES + base + 4);
            d[0] = d0.x; d[1] = d0.y; d[2] = d0.z; d[3] = d0.w;
            d[4] = d1.x; d[5] = d1.y; d[6] = d1.z; d[7] = d1.w;
            int4 s0 = *(const int4*)(ei + base);
            int4 s1 = *(const int4*)(ei + base + 4);
            s[0] = s0.x; s[1] = s0.y; s[2] = s0.z; s[3] = s0.w;
            s[4] = s1.x; s[5] = s1.y; s[6] = s1.z; s[7] = s1.w;
            float4 w0 = *(const float4*)(ew + base);
            float4 w1 = *(const float4*)(ew + base + 4);
            w[0] = w0.x; w[1] = w0.y; w[2] = w0.z; w[3] = w0.w;
            w[4] = w1.x; w[5] = w1.y; w[6] = w1.z; w[7] = w1.w;
        } else {
#pragma unroll
            for (int t = 0; t < 8; ++t) {
                bool v = (base + t) < N_EDGES;
                d[t] = v ? ei[N_EDGES + base + t] : -1;
                s[t] = v ? ei[base + t] : 0;
                w[t] = v ? ew[base + t] : 0.0f;
            }
        }

        int slot[8];
#pragma unroll
        for (int t = 0; t < 8; ++t) {
            bool act = (unsigned)(d[t] - lo) < (unsigned)NPG;
            slot[t] = act ? atomicAdd(cnt_ptr(bins, d[t]), 1) : CAP;
        }
#pragma unroll
        for (int t = 0; t < 8; ++t) {
            if (slot[t] < CAP_USE)
                bins[(size_t)d[t] * CAP + slot[t]] =
                    make_uint2((unsigned)s[t], __float_as_uint(w[t]));
        }
        return;
    }

    // ---- gemm role ----
    const int lane = tid & 63, wave = tid >> 6;
    const int row0 = (blockIdx.x - FILL_BLOCKS) * 64 + wave * 16;
    if (row0 >= N_NODES) return;

    const int m = lane & 15;             // A row within tile
    const int q = (lane >> 4) & 3;       // k quad
    const float* mrow = mean + (size_t)(row0 + m) * CH + q * 8;
    const float* srow = stdv + (size_t)(row0 + m) * CH + q * 8;

    short8 aM[2], aV[2];
#pragma unroll
    for (int h = 0; h < 2; ++h) {        // k = h*32 + q*8 + j
        float4 x0 = *(const float4*)(mrow + h * 32);
        float4 x1 = *(const float4*)(mrow + h * 32 + 4);
        float4 s0 = *(const float4*)(srow + h * 32);
        float4 s1 = *(const float4*)(srow + h * 32 + 4);
        aM[h][0] = (short)f2bf(x0.x); aM[h][1] = (short)f2bf(x0.y);
        aM[h][2] = (short)f2bf(x0.z); aM[h][3] = (short)f2bf(x0.w);
        aM[h][4] = (short)f2bf(x1.x); aM[h][5] = (short)f2bf(x1.y);
        aM[h][6] = (short)f2bf(x1.z); aM[h][7] = (short)f2bf(x1.w);
        aV[h][0] = (short)f2bf(s0.x * s0.x); aV[h][1] = (short)f2bf(s0.y * s0.y);
        aV[h][2] = (short)f2bf(s0.z * s0.z); aV[h][3] = (short)f2bf(s0.w * s0.w);
        aV[h][4] = (short)f2bf(s1.x * s1.x); aV[h][5] = (short)f2bf(s1.y * s1.y);
        aV[h][6] = (short)f2bf(s1.z * s1.z); aV[h][7] = (short)f2bf(s1.w * s1.w);
    }

    f32x4 accM[4], accV[4];
#pragma unroll
    for (int c = 0; c < 4; ++c) {
        accM[c] = (f32x4)0.0f;
        accV[c] = (f32x4)0.0f;
    }
#pragma unroll
    for (int c = 0; c < 4; ++c) {
#pragma unroll
        for (int h = 0; h < 2; ++h) {
            short8 bm = *(const short8*)(fragBm + ((c * 2 + h) * 64 + lane) * 8);
            short8 bv = *(const short8*)(fragBv + ((c * 2 + h) * 64 + lane) * 8);
            accM[c] = __builtin_amdgcn_mfma_f32_16x16x32_bf16(aM[h], bm, accM[c], 0, 0, 0);
            accV[c] = __builtin_amdgcn_mfma_f32_16x16x32_bf16(aV[h], bv, accV[c], 0, 0, 0);
        }
    }

    // C/D layout: col = lane&15, row = (lane>>4)*4 + reg  [m89-verified]
    const int rg = lane >> 4;
#pragma unroll
    for (int c = 0; c < 4; ++c) {
#pragma unroll
        for (int r = 0; r < 4; ++r) {
            int node = row0 + rg * 4 + r;
            sup[(size_t)node * CH + c * 16 + m] =
                f2bf(accM[c][r]) | (f2bf(accV[c][r]) << 16);
        }
    }
}

// ---------------------------------------------------------------------------
// Kernel C: pull-gather, XCD-affine (same g = blockIdx&7 mapping as fill, so
// a group's bins are L2-resident on its XCD). One wave per node, lane =
// channel, 8 independent sup loads in flight per iter. No atomics, no LDS.
// ---------------------------------------------------------------------------
__global__ __launch_bounds__(256) void gather_kernel(
    const uint2* __restrict__ bins,
    const unsigned* __restrict__ sup, float* __restrict__ out)
{
    const int g = blockIdx.x & (NGRP - 1);
    const int cid = blockIdx.x >> 3;
    const int wave = threadIdx.x >> 6;
    const int col = threadIdx.x & 63;
    const int loc = cid * 4 + wave;
    if (loc >= NPG) return;
    const int n = g * NPG + loc;

    int cnt = *(const int*)(bins + (size_t)n * CAP + 63);
    if (cnt > CAP_USE) cnt = CAP_USE;
    uint2 p = make_uint2(0u, 0u);
    if (col < cnt) p = bins[(size_t)n * CAP + col];

    float accM = 0.0f, accV = 0.0f;
    for (int i = 0; i < cnt; i += 8) {
        int   s[8];
        float w[8];
#pragma unroll
        for (int t = 0; t < 8; ++t) {
            bool v = (i + t < cnt);
            s[t] = v ? rl_i(p.x, i + t) : 0;
            w[t] = v ? __uint_as_float((unsigned)rl_i(p.y, i + t)) : 0.0f;
        }
        unsigned q[8];
#pragma unroll
        for (int t = 0; t < 8; ++t)
            q[t] = sup[(size_t)s[t] * CH + col];
#pragma unroll
        for (int t = 0; t < 8; ++t) {
            float mm = __uint_as_float(q[t] << 16);
            float vv = __uint_as_float(q[t] & 0xFFFF0000u);
            accM += w[t] * mm;
            accV += (w[t] * w[t]) * vv;
        }
    }
    out[(size_t)n * CH + col] = accM;
    out[OUT_OFF_STD + (size_t)n * CH + col] = sqrtf(expf(accV) + 1e-6f);
}

extern "C" void kernel_launch(void* const* d_in, const int* in_sizes, int n_in,
                              void* d_out, int out_size, void* d_ws, size_t ws_size,
                              hipStream_t stream)
{
    const float* mean  = (const float*)d_in[0];
    const float* stdv  = (const float*)d_in[1];
    const int*   ei    = (const int*)d_in[2];
    const float* ew    = (const float*)d_in[3];
    const float* mu_m  = (const float*)d_in[4];
    const float* ls_m  = (const float*)d_in[5];
    const float* eps_m = (const float*)d_in[6];
    const float* ls_s  = (const float*)d_in[8];
    const float* mu_s  = (const float*)d_in[7];
    const float* eps_s = (const float*)d_in[9];

    float* out = (float*)d_out;
    // layout (16B-aligned): sup | bins (counters embedded) | fragBm | fragBv
    unsigned*       sup    = (unsigned*)d_ws;                      // 3.2M u32
    uint2*          bins   = (uint2*)(sup + (size_t)N_NODES * CH); // 3.2M uint2
    unsigned short* fragBm = (unsigned short*)(bins + (size_t)N_NODES * CAP);
    unsigned short* fragBv = fragBm + CH * CH;

    wkl_kernel<<<ZERO_GRID, 256, 0, stream>>>(
        mu_m, ls_m, eps_m, mu_s, ls_s, eps_s,
        fragBm, fragBv, out + OUT_OFF_KL, bins);
    gemfill_kernel<<<FILL_BLOCKS + GEMM_BLOCKS, 256, 0, stream>>>(
        mean, stdv, fragBm, fragBv, ei, ew, bins, sup);
    gather_kernel<<<NGRP * GATHER_CHUNKS, 256, 0, stream>>>(bins, sup, out);
}

// Round 3
// 174.416 us; speedup vs baseline: 1.0843x; 1.0109x over previous
//
#include <hip/hip_runtime.h>

#define N_NODES 50000
#define N_EDGES 800000
#define CH 64
#define OUT_OFF_STD (N_NODES * CH)        // 3,200,000
#define OUT_OFF_KL  (2 * N_NODES * CH)    // 6,400,000
#define CAP 64                            // slots/node (512B region, 64B-line aligned)
#define CAP_USE 62                        // slot 63 = embedded counter

#define NGRP 8                            // XCD groups (blockIdx & 7 heuristic)
#define NPG 6250                          // nodes per group (8*6250 = 50000)
#define FILL_CHUNK 4096                   // 16 edges/thread * 256 threads
#define FILL_CHUNKS 196                   // 196*4096 = 802816 >= 800000
#define FILL_BLOCKS (NGRP * FILL_CHUNKS)  // 1568
#define GEMM_BLOCKS 782                   // ceil(50000/64)
#define GATHER_BLOCKS 2048                // persistent: 256 blocks/group
#define GWAVES_PG 1024                    // (2048/8)*4 waves per group
#define ZERO_GRID 208                     // blocks 8..207 zero counters XCD-affinely

typedef __attribute__((ext_vector_type(8))) short short8;
typedef __attribute__((ext_vector_type(4))) float f32x4;

__device__ __forceinline__ int rl_i(unsigned v, int lane) {
    return __builtin_amdgcn_readlane((int)v, lane);
}
// fp32 -> bf16 round-to-nearest-even (returns low 16 bits)
__device__ __forceinline__ unsigned f2bf(float f) {
    unsigned u = __float_as_uint(f);
    return (u + 0x7fffu + ((u >> 16) & 1u)) >> 16;
}
// per-node counter lives in slot 63 of the node's bins region -> one counter
// per 64B line; gather reads it for free from lane 63's row element.
__device__ __forceinline__ int* cnt_ptr(uint2* bins, int node) {
    return (int*)(bins + (size_t)node * CAP + 63);
}

// ---------------------------------------------------------------------------
// Kernel A: W + KL (block 0) + XCD-affine counter zeroing (blocks 8..207).
// fragB[((c*2+h)*64 + lane)*8 + j] = bf16(W[h*32+(lane>>4)*8+j][c*16+(lane&15)])
// ---------------------------------------------------------------------------
__global__ __launch_bounds__(256) void wkl_kernel(
    const float* __restrict__ mu_m, const float* __restrict__ ls_m,
    const float* __restrict__ eps_m,
    const float* __restrict__ mu_s, const float* __restrict__ ls_s,
    const float* __restrict__ eps_s,
    unsigned short* __restrict__ fragBm, unsigned short* __restrict__ fragBv,
    float* __restrict__ kl_out, uint2* __restrict__ bins)
{
    if (blockIdx.x != 0) {                // ---- counter-zero role ----
        if (blockIdx.x < 8) return;
        const int g = blockIdx.x & (NGRP - 1);
        const int loc = ((int)(blockIdx.x >> 3) - 1) * 256 + (int)threadIdx.x;
        if (loc < NPG) *cnt_ptr(bins, g * NPG + loc) = 0;
        return;
    }
    __shared__ unsigned short Wm[CH * CH];
    __shared__ unsigned short Wv[CH * CH];
    float kl = 0.0f;
    for (int i = threadIdx.x; i < CH * CH; i += 256) {
        float mu = mu_m[i], ls = ls_m[i];
        Wm[i] = (unsigned short)f2bf(mu + eps_m[i] * expf(ls));
        kl += 0.5f * (expf(2.0f * ls) + mu * mu - 2.0f * ls - 1.0f);
        mu = mu_s[i]; ls = ls_s[i];
        Wv[i] = (unsigned short)f2bf(mu + eps_s[i] * expf(ls));
        kl += 0.5f * (expf(2.0f * ls) + mu * mu - 2.0f * ls - 1.0f);
    }
    __syncthreads();
    for (int f = threadIdx.x; f < CH * CH; f += 256) {
        int j = f & 7, l = (f >> 3) & 63, ch = f >> 9;   // ch = c*2 + h
        int k = (ch & 1) * 32 + ((l >> 4) & 3) * 8 + j;
        int n = (ch >> 1) * 16 + (l & 15);
        fragBm[f] = Wm[k * CH + n];
        fragBv[f] = Wv[k * CH + n];
    }
    for (int off = 32; off > 0; off >>= 1)
        kl += __shfl_down(kl, off, 64);
    __shared__ float red[4];
    if ((threadIdx.x & 63) == 0) red[threadIdx.x >> 6] = kl;
    __syncthreads();
    if (threadIdx.x == 0)
        kl_out[0] = red[0] + red[1] + red[2] + red[3];
}

// ---------------------------------------------------------------------------
// Kernel B: fused XCD-affine fill + MFMA-GEMM. Zero LDS.
//  Fill: 16 edges/thread via dwordx4; all 16 atomics then all 16 stores
//  issued back-to-back -> 2x memory-level parallelism per wave vs R2.
// ---------------------------------------------------------------------------
__global__ __launch_bounds__(256) void gemfill_kernel(
    const float* __restrict__ mean, const float* __restrict__ stdv,
    const unsigned short* __restrict__ fragBm,
    const unsigned short* __restrict__ fragBv,
    const int* __restrict__ ei, const float* __restrict__ ew,
    uint2* __restrict__ bins, unsigned* __restrict__ sup)
{
    const int tid = threadIdx.x;

    if (blockIdx.x < FILL_BLOCKS) {      // ---- fill role, XCD-affine ----
        const int g = blockIdx.x & (NGRP - 1);
        const int chunk = blockIdx.x >> 3;
        const int base = chunk * FILL_CHUNK + tid * 16;
        const int lo = g * NPG;

        int d[16], s[16]; float w[16];
        if (base + 16 <= N_EDGES) {
#pragma unroll
            for (int h = 0; h < 4; ++h) {
                int4 dv = *(const int4*)(ei + N_EDGES + base + h * 4);
                d[h * 4 + 0] = dv.x; d[h * 4 + 1] = dv.y;
                d[h * 4 + 2] = dv.z; d[h * 4 + 3] = dv.w;
            }
#pragma unroll
            for (int h = 0; h < 4; ++h) {
                int4 sv = *(const int4*)(ei + base + h * 4);
                s[h * 4 + 0] = sv.x; s[h * 4 + 1] = sv.y;
                s[h * 4 + 2] = sv.z; s[h * 4 + 3] = sv.w;
            }
#pragma unroll
            for (int h = 0; h < 4; ++h) {
                float4 wv = *(const float4*)(ew + base + h * 4);
                w[h * 4 + 0] = wv.x; w[h * 4 + 1] = wv.y;
                w[h * 4 + 2] = wv.z; w[h * 4 + 3] = wv.w;
            }
        } else {
#pragma unroll
            for (int t = 0; t < 16; ++t) {
                bool v = (base + t) < N_EDGES;
                d[t] = v ? ei[N_EDGES + base + t] : -1;
                s[t] = v ? ei[base + t] : 0;
                w[t] = v ? ew[base + t] : 0.0f;
            }
        }

        int slot[16];
#pragma unroll
        for (int t = 0; t < 16; ++t) {
            bool act = (unsigned)(d[t] - lo) < (unsigned)NPG;
            slot[t] = act ? atomicAdd(cnt_ptr(bins, d[t]), 1) : CAP;
        }
#pragma unroll
        for (int t = 0; t < 16; ++t) {
            if (slot[t] < CAP_USE)
                bins[(size_t)d[t] * CAP + slot[t]] =
                    make_uint2((unsigned)s[t], __float_as_uint(w[t]));
        }
        return;
    }

    // ---- gemm role ----
    const int lane = tid & 63, wave = tid >> 6;
    const int row0 = (blockIdx.x - FILL_BLOCKS) * 64 + wave * 16;
    if (row0 >= N_NODES) return;

    const int m = lane & 15;             // A row within tile
    const int q = (lane >> 4) & 3;       // k quad
    const float* mrow = mean + (size_t)(row0 + m) * CH + q * 8;
    const float* srow = stdv + (size_t)(row0 + m) * CH + q * 8;

    short8 aM[2], aV[2];
#pragma unroll
    for (int h = 0; h < 2; ++h) {        // k = h*32 + q*8 + j
        float4 x0 = *(const float4*)(mrow + h * 32);
        float4 x1 = *(const float4*)(mrow + h * 32 + 4);
        float4 s0 = *(const float4*)(srow + h * 32);
        float4 s1 = *(const float4*)(srow + h * 32 + 4);
        aM[h][0] = (short)f2bf(x0.x); aM[h][1] = (short)f2bf(x0.y);
        aM[h][2] = (short)f2bf(x0.z); aM[h][3] = (short)f2bf(x0.w);
        aM[h][4] = (short)f2bf(x1.x); aM[h][5] = (short)f2bf(x1.y);
        aM[h][6] = (short)f2bf(x1.z); aM[h][7] = (short)f2bf(x1.w);
        aV[h][0] = (short)f2bf(s0.x * s0.x); aV[h][1] = (short)f2bf(s0.y * s0.y);
        aV[h][2] = (short)f2bf(s0.z * s0.z); aV[h][3] = (short)f2bf(s0.w * s0.w);
        aV[h][4] = (short)f2bf(s1.x * s1.x); aV[h][5] = (short)f2bf(s1.y * s1.y);
        aV[h][6] = (short)f2bf(s1.z * s1.z); aV[h][7] = (short)f2bf(s1.w * s1.w);
    }

    f32x4 accM[4], accV[4];
#pragma unroll
    for (int c = 0; c < 4; ++c) {
        accM[c] = (f32x4)0.0f;
        accV[c] = (f32x4)0.0f;
    }
#pragma unroll
    for (int c = 0; c < 4; ++c) {
#pragma unroll
        for (int h = 0; h < 2; ++h) {
            short8 bm = *(const short8*)(fragBm + ((c * 2 + h) * 64 + lane) * 8);
            short8 bv = *(const short8*)(fragBv + ((c * 2 + h) * 64 + lane) * 8);
            accM[c] = __builtin_amdgcn_mfma_f32_16x16x32_bf16(aM[h], bm, accM[c], 0, 0, 0);
            accV[c] = __builtin_amdgcn_mfma_f32_16x16x32_bf16(aV[h], bv, accV[c], 0, 0, 0);
        }
    }

    // C/D layout: col = lane&15, row = (lane>>4)*4 + reg  [m89-verified]
    const int rg = lane >> 4;
#pragma unroll
    for (int c = 0; c < 4; ++c) {
#pragma unroll
        for (int r = 0; r < 4; ++r) {
            int node = row0 + rg * 4 + r;
            sup[(size_t)node * CH + c * 16 + m] =
                f2bf(accM[c][r]) | (f2bf(accV[c][r]) << 16);
        }
    }
}

// ---------------------------------------------------------------------------
// Kernel C: persistent pull-gather, XCD-affine. One wave walks ~6 nodes
// (stride GWAVES_PG); next node's bins row is prefetched during current
// node's compute. Counter is lane 63's row element (no separate cnt load).
// 24-edge upfront batch (clamped idx, weight-zero padding) = one vmcnt wait
// for 98% of Poisson(16) nodes; rare 8-wide remainder for cnt>24.
// ---------------------------------------------------------------------------
__global__ __launch_bounds__(256) void gather_kernel(
    const uint2* __restrict__ bins,
    const unsigned* __restrict__ sup, float* __restrict__ out)
{
    const int g = blockIdx.x & (NGRP - 1);
    const int wid = ((int)(blockIdx.x >> 3)) * 4 + (int)(threadIdx.x >> 6);
    const int col = threadIdx.x & 63;
    const int nbase = g * NPG;

    int loc = wid;
    if (loc >= NPG) return;

    uint2 pnext = bins[(size_t)(nbase + loc) * CAP + col];

    for (; loc < NPG; loc += GWAVES_PG) {
        uint2 p = pnext;
        {
            int loc2 = loc + GWAVES_PG;
            if (loc2 < NPG)
                pnext = bins[(size_t)(nbase + loc2) * CAP + col];
        }
        int cnt = rl_i(p.x, 63);
        if (cnt > CAP_USE) cnt = CAP_USE;

        float accM = 0.0f, accV = 0.0f;
        if (cnt > 0) {
            unsigned q[24];
#pragma unroll
            for (int t = 0; t < 24; ++t) {
                int e = (t < cnt) ? t : (cnt - 1);
                q[t] = sup[(size_t)(unsigned)rl_i(p.x, e) * CH + col];
            }
#pragma unroll
            for (int t = 0; t < 24; ++t) {
                int e = (t < cnt) ? t : (cnt - 1);
                float wt = (t < cnt)
                    ? __uint_as_float((unsigned)rl_i(p.y, e)) : 0.0f;
                accM += wt * __uint_as_float(q[t] << 16);
                accV += (wt * wt) * __uint_as_float(q[t] & 0xFFFF0000u);
            }
            for (int i = 24; i < cnt; i += 8) {   // rare tail (P ~2%)
                unsigned qq[8]; float ww[8];
#pragma unroll
                for (int t = 0; t < 8; ++t) {
                    int e = (i + t < cnt) ? (i + t) : (cnt - 1);
                    qq[t] = sup[(size_t)(unsigned)rl_i(p.x, e) * CH + col];
                    ww[t] = (i + t < cnt)
                        ? __uint_as_float((unsigned)rl_i(p.y, e)) : 0.0f;
                }
#pragma unroll
                for (int t = 0; t < 8; ++t) {
                    accM += ww[t] * __uint_as_float(qq[t] << 16);
                    accV += (ww[t] * ww[t]) * __uint_as_float(qq[t] & 0xFFFF0000u);
                }
            }
        }
        const int n = nbase + loc;
        __builtin_nontemporal_store(accM, &out[(size_t)n * CH + col]);
        __builtin_nontemporal_store(sqrtf(expf(accV) + 1e-6f),
                                    &out[OUT_OFF_STD + (size_t)n * CH + col]);
    }
}

extern "C" void kernel_launch(void* const* d_in, const int* in_sizes, int n_in,
                              void* d_out, int out_size, void* d_ws, size_t ws_size,
                              hipStream_t stream)
{
    const float* mean  = (const float*)d_in[0];
    const float* stdv  = (const float*)d_in[1];
    const int*   ei    = (const int*)d_in[2];
    const float* ew    = (const float*)d_in[3];
    const float* mu_m  = (const float*)d_in[4];
    const float* ls_m  = (const float*)d_in[5];
    const float* eps_m = (const float*)d_in[6];
    const float* ls_s  = (const float*)d_in[8];
    const float* mu_s  = (const float*)d_in[7];
    const float* eps_s = (const float*)d_in[9];

    float* out = (float*)d_out;
    // layout (16B-aligned): sup | bins (counters embedded) | fragBm | fragBv
    unsigned*       sup    = (unsigned*)d_ws;                      // 3.2M u32
    uint2*          bins   = (uint2*)(sup + (size_t)N_NODES * CH); // 3.2M uint2
    unsigned short* fragBm = (unsigned short*)(bins + (size_t)N_NODES * CAP);
    unsigned short* fragBv = fragBm + CH * CH;

    wkl_kernel<<<ZERO_GRID, 256, 0, stream>>>(
        mu_m, ls_m, eps_m, mu_s, ls_s, eps_s,
        fragBm, fragBv, out + OUT_OFF_KL, bins);
    gemfill_kernel<<<FILL_BLOCKS + GEMM_BLOCKS, 256, 0, stream>>>(
        mean, stdv, fragBm, fragBv, ei, ew, bins, sup);
    gather_kernel<<<GATHER_BLOCKS, 256, 0, stream>>>(bins, sup, out);
}